// Round 3
// baseline (58.380 us; speedup 1.0000x reference)
//
#include <hip/hip_runtime.h>
#include <hip/hip_cooperative_groups.h>

namespace cg = cooperative_groups;

// Single cooperative dispatch:
//   phase 1: blocks 0..143 build transposed coeff-diff matrix ws[k][b] (k=0..143, b=0..63);
//            block 0 zeroes out[0].
//   grid.sync()
//   phase 2: block r (0..203) = landmark-row: lane b computes
//            diff = base_row[.] . ws[.][b]  (coalesced ws reads, uniform row reads),
//            butterfly-reduce w*diff^2, one atomicAdd per block.

#define NUM_LM 68
#define NROWS 204
#define K_ID 80
#define K_EXP 64
#define K_TOT 144

__device__ __constant__ int LM_IDX[NUM_LM] = {
    27440, 27208, 27608, 27816, 35472, 34766, 34312, 34022, 33838, 33654,
    33375, 32939, 32244, 16264, 16467, 16888, 16644, 31716, 31056, 30662,
    30454, 30288, 29549, 29382, 29177, 28787, 28111,  8161,  8177,  8187,
     8192,  9883,  9163,  8204,  7243,  6515, 14066, 12383, 11353, 10455,
    11492, 12653,  5828,  4920,  3886,  2215,  3640,  4801, 10795, 10395,
     8935,  8215,  7495,  6025,  5522,  6915,  7636,  8236,  8836,  9555,
    10537,  9064,  8223,  7384,  5909,  7629,  8229,  8829
};

__global__ __launch_bounds__(64) void fused_geo_loss(
        const float* __restrict__ alpha,
        const float* __restrict__ delta,
        const float* __restrict__ ref_alpha,
        const float* __restrict__ delta_pred,
        const float* __restrict__ id_base,
        const float* __restrict__ exp_base,
        float* __restrict__ ws,     // K_TOT*64 floats
        float* __restrict__ out) {
    const int bid = blockIdx.x;
    const int t   = threadIdx.x;    // lane = batch

    // ---- phase 1: coeff diffs, transposed ----
    if (bid == 0 && t == 0) out[0] = 0.0f;
    if (bid < K_TOT) {
        const int k = bid;
        float v;
        if (k < K_ID)
            v = alpha[t * K_ID + k] - ref_alpha[t * K_ID + k];
        else
            v = delta[t * K_EXP + (k - K_ID)] - delta_pred[t * K_EXP + (k - K_ID)];
        ws[k * 64 + t] = v;
    }
    __threadfence();
    cg::this_grid().sync();

    // ---- phase 2: per-row dot over 144 coeffs, 64 batches ----
    const int l = bid / 3;
    const int c = bid - 3 * l;
    const long long row = 3LL * LM_IDX[l] + c;
    const float* __restrict__ idr = id_base  + row * K_ID;   // wave-uniform
    const float* __restrict__ exr = exp_base + row * K_EXP;  // wave-uniform
    const float* __restrict__ cw  = ws + t;

    float d0 = 0.f, d1 = 0.f, d2 = 0.f, d3 = 0.f;
    #pragma unroll
    for (int k = 0; k < K_ID; k += 4) {
        d0 = fmaf(idr[k + 0], cw[(k + 0) * 64], d0);
        d1 = fmaf(idr[k + 1], cw[(k + 1) * 64], d1);
        d2 = fmaf(idr[k + 2], cw[(k + 2) * 64], d2);
        d3 = fmaf(idr[k + 3], cw[(k + 3) * 64], d3);
    }
    #pragma unroll
    for (int k = 0; k < K_EXP; k += 4) {
        d0 = fmaf(exr[k + 0], cw[(K_ID + k + 0) * 64], d0);
        d1 = fmaf(exr[k + 1], cw[(K_ID + k + 1) * 64], d1);
        d2 = fmaf(exr[k + 2], cw[(K_ID + k + 2) * 64], d2);
        d3 = fmaf(exr[k + 3], cw[(K_ID + k + 3) * 64], d3);
    }
    const float diff = (d0 + d1) + (d2 + d3);

    const float w = ((l >= 17 && l < 27) || l >= 36) ? 50.0f : 1.0f;
    float v = w * diff * diff;

    #pragma unroll
    for (int off = 32; off > 0; off >>= 1)
        v += __shfl_down(v, off, 64);

    if (t == 0)
        atomicAdd(out, v * (1.0f / 68.0f));
}

extern "C" void kernel_launch(void* const* d_in, const int* in_sizes, int n_in,
                              void* d_out, int out_size, void* d_ws, size_t ws_size,
                              hipStream_t stream) {
    const float* alpha      = (const float*)d_in[0];
    const float* delta      = (const float*)d_in[1];
    const float* ref_alpha  = (const float*)d_in[2];
    const float* delta_pred = (const float*)d_in[3];
    const float* id_base    = (const float*)d_in[4];
    const float* exp_base   = (const float*)d_in[5];
    float* out = (float*)d_out;
    float* ws  = (float*)d_ws;   // needs K_TOT*64*4 = 36,864 B

    void* args[] = { (void*)&alpha, (void*)&delta, (void*)&ref_alpha,
                     (void*)&delta_pred, (void*)&id_base, (void*)&exp_base,
                     (void*)&ws, (void*)&out };

    hipLaunchCooperativeKernel((void*)fused_geo_loss, dim3(NROWS), dim3(64),
                               args, 0, stream);
}

// Round 4
// 11.606 us; speedup vs baseline: 5.0302x; 5.0302x over previous
//
#include <hip/hip_runtime.h>

// Single-dispatch, single-block geo landmark loss via bf16 MFMA.
//   D[r][b] = sum_k R[r][k] * cd[k][b],  r<204 (pad 208), k<144 (pad 160), b<64
//   loss = sum_{r,b} w[r/3] * D[r][b]^2 / 68
// R rows gathered global->VGPR per wave; cd staged transposed in LDS as bf16.
// No atomics, no workspace, no zero-init requirements -> graph-replay safe.

#define NUM_LM 68
#define K_ID 80
#define K_EXP 64
#define NROWS 204
#define NWAVES 13
#define BLOCK (NWAVES * 64)     // 832 threads
#define CD_STRIDE 168           // bf16 elems per batch row (padded from 160)

typedef short bf16x8 __attribute__((ext_vector_type(8)));
typedef float f32x4  __attribute__((ext_vector_type(4)));

__device__ __constant__ int LM_IDX[NUM_LM] = {
    27440, 27208, 27608, 27816, 35472, 34766, 34312, 34022, 33838, 33654,
    33375, 32939, 32244, 16264, 16467, 16888, 16644, 31716, 31056, 30662,
    30454, 30288, 29549, 29382, 29177, 28787, 28111,  8161,  8177,  8187,
     8192,  9883,  9163,  8204,  7243,  6515, 14066, 12383, 11353, 10455,
    11492, 12653,  5828,  4920,  3886,  2215,  3640,  4801, 10795, 10395,
     8935,  8215,  7495,  6025,  5522,  6915,  7636,  8236,  8836,  9555,
    10537,  9064,  8223,  7384,  5909,  7629,  8229,  8829
};

__device__ __forceinline__ unsigned short f2bf(float f) {
    union { float f; unsigned u; } v; v.f = f;
    unsigned r = v.u + 0x7FFFu + ((v.u >> 16) & 1u);   // round-nearest-even
    return (unsigned short)(r >> 16);
}

__global__ __launch_bounds__(BLOCK) void fused_geo_loss(
        const float* __restrict__ alpha,
        const float* __restrict__ delta,
        const float* __restrict__ ref_alpha,
        const float* __restrict__ delta_pred,
        const float* __restrict__ id_base,
        const float* __restrict__ exp_base,
        float* __restrict__ out) {
    __shared__ __align__(16) unsigned short cdT[64 * CD_STRIDE];
    __shared__ float red[NWAVES];

    const int tid = threadIdx.x;
    const int w   = tid >> 6;      // wave = M-tile
    const int l   = tid & 63;      // lane
    const int mh  = l & 15;        // row-hat within tile (A) / col-hat (B)
    const int g   = l >> 4;        // k-group

    // ---- A-operand gather (global -> VGPR), issued before LDS staging ----
    const int  m     = 16 * w + mh;       // 0..207
    const bool valid = m < NROWS;
    const int  lmi   = valid ? (m / 3) : 0;
    const int  cc    = m - 3 * (m / 3);
    const long long vrow = 3LL * LM_IDX[lmi] + cc;
    const float* __restrict__ idp = id_base  + vrow * K_ID;
    const float* __restrict__ exq = exp_base + vrow * K_EXP;

    float4 af[5][2];
    #pragma unroll
    for (int s = 0; s < 5; ++s) {
        const int k0 = 32 * s + g * 8;    // lane's 8-wide k-chunk, never straddles
        if (valid && k0 < K_ID) {
            af[s][0] = *(const float4*)(idp + k0);
            af[s][1] = *(const float4*)(idp + k0 + 4);
        } else if (valid && k0 < K_ID + K_EXP) {
            af[s][0] = *(const float4*)(exq + (k0 - K_ID));
            af[s][1] = *(const float4*)(exq + (k0 - K_ID) + 4);
        } else {
            af[s][0] = float4{0.f, 0.f, 0.f, 0.f};
            af[s][1] = float4{0.f, 0.f, 0.f, 0.f};
        }
    }

    // ---- stage coeff diffs transposed into LDS as bf16: cdT[b][k] ----
    for (int i = tid; i < (64 * K_ID) / 4; i += BLOCK) {        // 1280 float4
        float4 a4 = ((const float4*)alpha)[i];
        float4 r4 = ((const float4*)ref_alpha)[i];
        const int e = i * 4, b = e / K_ID, k = e - b * K_ID;
        unsigned short* p = &cdT[b * CD_STRIDE + k];
        p[0] = f2bf(a4.x - r4.x); p[1] = f2bf(a4.y - r4.y);
        p[2] = f2bf(a4.z - r4.z); p[3] = f2bf(a4.w - r4.w);
    }
    for (int i = tid; i < (64 * K_EXP) / 4; i += BLOCK) {       // 1024 float4
        float4 d4 = ((const float4*)delta)[i];
        float4 q4 = ((const float4*)delta_pred)[i];
        const int e = i * 4, b = e >> 6, k = e & 63;
        unsigned short* p = &cdT[b * CD_STRIDE + K_ID + k];
        p[0] = f2bf(d4.x - q4.x); p[1] = f2bf(d4.y - q4.y);
        p[2] = f2bf(d4.z - q4.z); p[3] = f2bf(d4.w - q4.w);
    }
    for (int i = tid; i < 64 * 16; i += BLOCK) {                // zero k=144..159
        const int b = i >> 4, k = 144 + (i & 15);
        cdT[b * CD_STRIDE + k] = 0;
    }
    __syncthreads();

    // ---- MFMA: 5 k-steps x 4 N-tiles per wave ----
    f32x4 acc[4];
    const f32x4 z4 = {0.f, 0.f, 0.f, 0.f};
    acc[0] = z4; acc[1] = z4; acc[2] = z4; acc[3] = z4;

    #pragma unroll
    for (int s = 0; s < 5; ++s) {
        bf16x8 a;
        const float* fp = (const float*)&af[s][0];
        #pragma unroll
        for (int j = 0; j < 8; ++j) a[j] = (short)f2bf(fp[j]);
        #pragma unroll
        for (int t = 0; t < 4; ++t) {
            const bf16x8 b =
                *(const bf16x8*)&cdT[(16 * t + mh) * CD_STRIDE + 32 * s + g * 8];
            acc[t] = __builtin_amdgcn_mfma_f32_16x16x32_bf16(a, b, acc[t], 0, 0, 0);
        }
    }

    // ---- weighted square-sum; D layout: col=lane&15, row=(lane>>4)*4+reg ----
    float v = 0.f;
    #pragma unroll
    for (int q = 0; q < 4; ++q) {
        const int row = 16 * w + 4 * g + q;
        float wq = 0.f;
        if (row < NROWS) {
            const int li = row / 3;
            wq = ((li >= 17 && li < 27) || li >= 36) ? 50.f : 1.f;
        }
        float sq = 0.f;
        #pragma unroll
        for (int t = 0; t < 4; ++t) sq += acc[t][q] * acc[t][q];
        v += wq * sq;
    }
    #pragma unroll
    for (int off = 32; off; off >>= 1) v += __shfl_down(v, off, 64);
    if (l == 0) red[w] = v;
    __syncthreads();
    if (tid == 0) {
        float tot = 0.f;
        #pragma unroll
        for (int i = 0; i < NWAVES; ++i) tot += red[i];
        out[0] = tot * (1.0f / 68.0f);
    }
}

extern "C" void kernel_launch(void* const* d_in, const int* in_sizes, int n_in,
                              void* d_out, int out_size, void* d_ws, size_t ws_size,
                              hipStream_t stream) {
    const float* alpha      = (const float*)d_in[0];
    const float* delta      = (const float*)d_in[1];
    const float* ref_alpha  = (const float*)d_in[2];
    const float* delta_pred = (const float*)d_in[3];
    const float* id_base    = (const float*)d_in[4];
    const float* exp_base   = (const float*)d_in[5];
    float* out = (float*)d_out;

    fused_geo_loss<<<dim3(1), dim3(BLOCK), 0, stream>>>(
        alpha, delta, ref_alpha, delta_pred, id_base, exp_base, out);
}